// Round 2
// baseline (405.621 us; speedup 1.0000x reference)
//
#include <hip/hip_runtime.h>

// CoarseMatching dual-softmax on MI355X — round 4.
// N=2, L=S=4800, C=256. sim = f0.f1^T/(256*0.1); conf = softmax_l * softmax_s.
// GEMM: f16 hi/lo 2-term split -> K=512 f16 MFMA GEMM.
// RECOMPUTE STRUCTURE: pass 0 = sims+exp -> atomic rs/cs (no e-write);
// pass 1 = recompute sims+exp, conf = e^2*(1/rs)*(1/cs) written once, row-max
// via atomicMax(int) on nonneg floats. Eliminates 184 MB e-write + 184 MB
// conf-pass read + inv/conf kernels. A2/B2 (19.9 MB) stay L3-resident.
// K-loop: BK=32 double-buffered LDS (32 KB), 2-phase: issue next-tile
// global_load_lds, compute current, single barrier per step (counted-drain
// overlap). XOR 16B-slot swizzle -> conflict-free ds_read_b128.

#define Ncst 2
#define Lc 4800
#define Sc 4800
#define Cc 256
#define K2 512          // 2*C expanded K (f16 hi|lo for A, hi|hi for B)
#define LP 4864         // 4800 padded to 38*128
#define THRC 0.2f

typedef float f32x4 __attribute__((ext_vector_type(4)));
typedef _Float16 f16x8 __attribute__((ext_vector_type(8)));

#define AS1(p) ((__attribute__((address_space(1))) void*)(p))
#define AS3(p) ((__attribute__((address_space(3))) void*)(p))

// ---------------- init: zero the atomic accumulators -------------------------
__global__ __launch_bounds__(256) void init_kernel(
    float* __restrict__ rs, float* __restrict__ cs, float* __restrict__ rcm)
{
    int i = blockIdx.x * 256 + threadIdx.x;
    if (i < Ncst * Lc) { rs[i] = 0.f; cs[i] = 0.f; rcm[i] = 0.f; }
}

// ---------------- conversion: A2 [N][LP][512], B2 [N][LP][512] f16 -----------
// A2 segments: [a_hi | a_lo]; B2: [b_hi | b_hi]
// => dot over 512 = hi.hi + lo.hi.  Vectorized: 8 k per thread.
__global__ __launch_bounds__(256) void convert_kernel(
    const float* __restrict__ f0, const float* __restrict__ f1,
    unsigned short* __restrict__ A2, unsigned short* __restrict__ B2)
{
    int idx = blockIdx.x * 256 + threadIdx.x;      // over N*LP*(C/8)
    if (idx >= Ncst * LP * (Cc / 8)) return;
    int k8  = idx & (Cc / 8 - 1);                  // 0..31
    int row = (idx >> 5) % LP;
    int n   = idx / (LP * (Cc / 8));
    size_t base = ((size_t)n * LP + row) * K2 + k8 * 8;

    float av[8], bv[8];
    if (row < Lc) {
        const float4* pa = (const float4*)(f0 + ((size_t)n * Lc + row) * Cc + k8 * 8);
        float4 a0 = pa[0], a1 = pa[1];
        av[0]=a0.x; av[1]=a0.y; av[2]=a0.z; av[3]=a0.w;
        av[4]=a1.x; av[5]=a1.y; av[6]=a1.z; av[7]=a1.w;
        const float4* pb = (const float4*)(f1 + ((size_t)n * Sc + row) * Cc + k8 * 8);
        float4 b0 = pb[0], b1 = pb[1];
        bv[0]=b0.x; bv[1]=b0.y; bv[2]=b0.z; bv[3]=b0.w;
        bv[4]=b1.x; bv[5]=b1.y; bv[6]=b1.z; bv[7]=b1.w;
    } else {
        for (int i = 0; i < 8; ++i) { av[i] = 0.f; bv[i] = 0.f; }
    }

    _Float16 ahi[8], alo[8], bhi[8];
#pragma unroll
    for (int i = 0; i < 8; ++i) {
        _Float16 h = (_Float16)av[i];
        ahi[i] = h;
        alo[i] = (_Float16)(av[i] - (float)h);
        bhi[i] = (_Float16)bv[i];
    }
    *(uint4*)&A2[base]       = *(uint4*)ahi;
    *(uint4*)&A2[base + 256] = *(uint4*)alo;
    *(uint4*)&B2[base]       = *(uint4*)bhi;
    *(uint4*)&B2[base + 256] = *(uint4*)bhi;
}

// ---------------- GEMM passes ------------------------------------------------
// 128x128 tile, 4 waves (2x2), each wave 64x64 via 4x4 grid of 16x16x32 MFMAs.
// BK=32, double-buffered 8KB stages, 16 K-steps, 1 barrier per step.
// LDS slot layout (per 8KB buffer): 512 slots of 16B; slot s holds
// (row = s>>2, q = (s&3) ^ ((row>>1)&3)); fragment ds_read_b128 is 2 lanes/bank.
// PASS 0: e = exp(alpha*sim); atomicAdd row sums rs, col sums cs.
// PASS 1: recompute e; conf = e^2*(1/rs)*(1/cs); write conf; atomicMax rcm.
template <int PASS>
__global__ __launch_bounds__(256) void gemm_kernel(
    const unsigned short* __restrict__ A2, const unsigned short* __restrict__ B2,
    float* __restrict__ out, float* __restrict__ rs, float* __restrict__ cs,
    int* __restrict__ rcm)
{
    __shared__ unsigned short lA[2][128 * 32];   // 2 x 8 KB
    __shared__ unsigned short lB[2][128 * 32];

    // bijective XCD-aware swizzle: grid = 38*38*2 = 2888 = 8*361
    int flat = blockIdx.x + 38 * blockIdx.y + 1444 * blockIdx.z;
    int m    = (flat & 7) * 361 + (flat >> 3);
    const int tn = m % 38;
    const int tm = (m / 38) % 38;
    const int n  = m / 1444;

    const int tid  = threadIdx.x;
    const int wave = tid >> 6;
    const int lane = tid & 63;
    const int wm   = wave >> 1;     // 0..1
    const int wn   = wave & 1;      // 0..1
    const int ml   = lane & 15;
    const int kq   = lane >> 4;     // 0..3

    const unsigned short* Ab = A2 + ((size_t)n * LP + (size_t)tm * 128) * K2;
    const unsigned short* Bb = B2 + ((size_t)n * LP + (size_t)tn * 128) * K2;

    // staging addresses: 2 slots per matrix per thread
    const int s0 = (wave * 2 + 0) * 64 + lane;        // 0..511
    const int s1 = (wave * 2 + 1) * 64 + lane;
    const int r0_ = s0 >> 2, q0 = (s0 & 3) ^ ((r0_ >> 1) & 3);
    const int r1_ = s1 >> 2, q1 = (s1 & 3) ^ ((r1_ >> 1) & 3);
    const unsigned short* gA0 = Ab + (size_t)r0_ * K2 + q0 * 8;
    const unsigned short* gA1 = Ab + (size_t)r1_ * K2 + q1 * 8;
    const unsigned short* gB0 = Bb + (size_t)r0_ * K2 + q0 * 8;
    const unsigned short* gB1 = Bb + (size_t)r1_ * K2 + q1 * 8;

    // fragment LDS element offsets (fixed per thread; +4096 toggles buffer)
    int aoff[4], boff[4];
#pragma unroll
    for (int i = 0; i < 4; ++i) {
        int arow = wm * 64 + i * 16 + ml;
        aoff[i] = (arow * 4 + (kq ^ ((arow >> 1) & 3))) * 8;
        int brow = wn * 64 + i * 16 + ml;
        boff[i] = (brow * 4 + (kq ^ ((brow >> 1) & 3))) * 8;
    }

    f32x4 acc[4][4] = {};

    // prologue: stage tile 0 into buffer 0
    __builtin_amdgcn_global_load_lds(AS1(gA0), AS3(&lA[0][s0 * 8]), 16, 0, 0);
    __builtin_amdgcn_global_load_lds(AS1(gA1), AS3(&lA[0][s1 * 8]), 16, 0, 0);
    __builtin_amdgcn_global_load_lds(AS1(gB0), AS3(&lB[0][s0 * 8]), 16, 0, 0);
    __builtin_amdgcn_global_load_lds(AS1(gB1), AS3(&lB[0][s1 * 8]), 16, 0, 0);
    __syncthreads();

#pragma unroll
    for (int t = 0; t < 16; ++t) {
        const int buf = t & 1;
        if (t < 15) {   // issue next-tile loads; they land during the MFMAs
            const int ko = (t + 1) * 32;
            __builtin_amdgcn_global_load_lds(AS1(gA0 + ko), AS3(&lA[buf ^ 1][s0 * 8]), 16, 0, 0);
            __builtin_amdgcn_global_load_lds(AS1(gA1 + ko), AS3(&lA[buf ^ 1][s1 * 8]), 16, 0, 0);
            __builtin_amdgcn_global_load_lds(AS1(gB0 + ko), AS3(&lB[buf ^ 1][s0 * 8]), 16, 0, 0);
            __builtin_amdgcn_global_load_lds(AS1(gB1 + ko), AS3(&lB[buf ^ 1][s1 * 8]), 16, 0, 0);
        }
        f16x8 af[4], bfr[4];
#pragma unroll
        for (int i = 0; i < 4; ++i) {
            af[i]  = *(const f16x8*)&lA[buf][aoff[i]];
            bfr[i] = *(const f16x8*)&lB[buf][boff[i]];
        }
#pragma unroll
        for (int i = 0; i < 4; ++i)
#pragma unroll
            for (int j = 0; j < 4; ++j)
                acc[i][j] = __builtin_amdgcn_mfma_f32_16x16x32_f16(af[i], bfr[j], acc[i][j], 0, 0, 0);
        __syncthreads();   // drains vmcnt: next-tile loads had full MFMA phase
    }

    // D[row][col]: col = lane&15, row = (lane>>4)*4 + r
    const float alpha = 5.0f / 128.0f;          // 1/(256*0.1), exact in fp32

    if constexpr (PASS == 0) {
        // e in place of sim; accumulate row/col sums
#pragma unroll
        for (int i = 0; i < 4; ++i) {
#pragma unroll
            for (int r = 0; r < 4; ++r) {
                int gl = tm * 128 + wm * 64 + i * 16 + kq * 4 + r;
                bool rok = gl < Lc;
#pragma unroll
                for (int j = 0; j < 4; ++j) {
                    int gs = tn * 128 + wn * 64 + j * 16 + ml;
                    bool ok = rok && (gs < Sc);
                    acc[i][j][r] = ok ? __expf(acc[i][j][r] * alpha) : 0.f;
                }
            }
        }
        // row sums: reduce over j and ml lanes (xor 1,2,4,8 stays in quarter)
#pragma unroll
        for (int i = 0; i < 4; ++i) {
#pragma unroll
            for (int r = 0; r < 4; ++r) {
                float rp = acc[i][0][r] + acc[i][1][r] + acc[i][2][r] + acc[i][3][r];
                rp += __shfl_xor(rp, 1);
                rp += __shfl_xor(rp, 2);
                rp += __shfl_xor(rp, 4);
                rp += __shfl_xor(rp, 8);
                int gl = tm * 128 + wm * 64 + i * 16 + kq * 4 + r;
                if (ml == 0 && gl < Lc) atomicAdd(&rs[(size_t)n * Lc + gl], rp);
            }
        }
        // col sums: reduce over i,r and kq (xor 16, 32)
#pragma unroll
        for (int j = 0; j < 4; ++j) {
            float cp = 0.f;
#pragma unroll
            for (int i = 0; i < 4; ++i)
#pragma unroll
                for (int r = 0; r < 4; ++r) cp += acc[i][j][r];
            cp += __shfl_xor(cp, 16);
            cp += __shfl_xor(cp, 32);
            int gs = tn * 128 + wn * 64 + j * 16 + ml;
            if (kq == 0 && gs < Sc) atomicAdd(&cs[(size_t)n * Sc + gs], cp);
        }
    } else {
        // conf = e^2 * (1/rs) * (1/cs); write final conf; row-max via atomicMax
        float cin[4];
#pragma unroll
        for (int j = 0; j < 4; ++j) {
            int gs = tn * 128 + wn * 64 + j * 16 + ml;
            cin[j] = (gs < Sc) ? 1.0f / cs[(size_t)n * Sc + gs] : 0.f;
        }
#pragma unroll
        for (int i = 0; i < 4; ++i) {
#pragma unroll
            for (int r = 0; r < 4; ++r) {
                int gl = tm * 128 + wm * 64 + i * 16 + kq * 4 + r;
                bool rok = gl < Lc;
                float ri = rok ? 1.0f / rs[(size_t)n * Lc + gl] : 0.f;
                float rmax = 0.f;
#pragma unroll
                for (int j = 0; j < 4; ++j) {
                    int gs = tn * 128 + wn * 64 + j * 16 + ml;
                    bool ok = rok && (gs < Sc);
                    float ev = __expf(acc[i][j][r] * alpha);
                    float c  = ev * ev * ri * cin[j];
                    if (!ok) c = 0.f;
                    if (ok) out[((size_t)n * Lc + gl) * Sc + gs] = c;
                    rmax = fmaxf(rmax, c);
                }
                rmax = fmaxf(rmax, __shfl_xor(rmax, 1));
                rmax = fmaxf(rmax, __shfl_xor(rmax, 2));
                rmax = fmaxf(rmax, __shfl_xor(rmax, 4));
                rmax = fmaxf(rmax, __shfl_xor(rmax, 8));
                if (ml == 0 && rok)
                    atomicMax(&rcm[(size_t)n * Lc + gl], __float_as_int(rmax));
            }
        }
    }
}

// ---------------- finalize: threshold + border + mutual-NN -------------------
// Gated by rowmax_conf > THR (any mask-true entry must equal rowmax > THR).
__global__ __launch_bounds__(256) void finalize_kernel(
    const float* __restrict__ conf, const float* __restrict__ rcm,
    const int* __restrict__ h0p, const int* __restrict__ w0p,
    const int* __restrict__ h1p, const int* __restrict__ w1p,
    float* __restrict__ out_match, float* __restrict__ out_j, float* __restrict__ out_mconf)
{
    int i = blockIdx.x * 256 + threadIdx.x;      // n*Lc + l
    if (i >= Ncst * Lc) return;
    int n = i / Lc, l = i % Lc;
    float mm = rcm[i];
    float fm = 0.f, fj = 0.f, fc = 0.f;
    if (mm > THRC) {
        int w0 = *w0p, w1 = *w1p;
        if ((l / w0) >= 2 && (l % w0) >= 2) {
            const float* rowp = conf + ((size_t)n * Lc + l) * Sc;
            for (int s = 0; s < Sc; ++s) {
                float c = rowp[s];
                if (c == mm && (s / w1) >= 2 && (s % w1) >= 2) {
                    bool ismax = true;
                    const float* colp = conf + (size_t)n * Lc * Sc + s;
                    for (int lp = 0; lp < Lc; ++lp) {
                        if (colp[(size_t)lp * Sc] > c) { ismax = false; break; }
                    }
                    if (ismax) { fm = 1.f; fj = (float)s; fc = c; break; }
                }
            }
        }
    }
    out_match[i] = fm; out_j[i] = fj; out_mconf[i] = fc;
}

extern "C" void kernel_launch(void* const* d_in, const int* in_sizes, int n_in,
                              void* d_out, int out_size, void* d_ws, size_t ws_size,
                              hipStream_t stream) {
    const float* f0 = (const float*)d_in[0];
    const float* f1 = (const float*)d_in[1];
    const int* h0p = (const int*)d_in[2];
    const int* w0p = (const int*)d_in[3];
    const int* h1p = (const int*)d_in[4];
    const int* w1p = (const int*)d_in[5];

    // workspace layout (bytes); total ~20.0 MB
    char* ws = (char*)d_ws;
    unsigned short* A2 = (unsigned short*)ws;                  // 9,961,472 B
    unsigned short* B2 = (unsigned short*)(ws + 9961472);      // 9,961,472 B
    float* rs  = (float*)(ws + 19922944);                      // 38,400 B each
    float* cs  = (float*)(ws + 19961344);
    float* rcm = (float*)(ws + 19999744);

    float* conf      = (float*)d_out;                          // [N][L][S]
    float* out_match = conf + (size_t)Ncst * Lc * Sc;
    float* out_j     = out_match + Ncst * Lc;
    float* out_mconf = out_j + Ncst * Lc;

    init_kernel<<<(Ncst * Lc + 255) / 256, 256, 0, stream>>>(rs, cs, rcm);

    convert_kernel<<<(Ncst * LP * (Cc / 8) + 255) / 256, 256, 0, stream>>>(f0, f1, A2, B2);

    dim3 gg(LP / 128, LP / 128, Ncst);   // 38 x 38 x 2
    gemm_kernel<0><<<gg, 256, 0, stream>>>(A2, B2, nullptr, rs, cs, nullptr);
    gemm_kernel<1><<<gg, 256, 0, stream>>>(A2, B2, conf, rs, cs, (int*)rcm);

    finalize_kernel<<<(Ncst * Lc + 255) / 256, 256, 0, stream>>>(
        conf, rcm, h0p, w0p, h1p, w1p, out_match, out_j, out_mconf);
}

// Round 3
// 338.881 us; speedup vs baseline: 1.1969x; 1.1969x over previous
//
#include <hip/hip_runtime.h>

// CoarseMatching dual-softmax on MI355X — round 5.
// N=2, L=S=4800, C=256. sim = f0.f1^T/(256*0.1); conf = softmax_l * softmax_s.
// GEMM: f16 hi/lo 2-term split -> K=512 f16 MFMA GEMM (K2=512).
// Structure: materialize e (round-3, best-known) but GEMM ported to the
// 8-phase 256^2 schedule (T2 swizzle + T3/T4 counted vmcnt + T5 setprio):
//   256x256 tile, BK=64, 8 waves (2Mx4N), 128KB LDS (2buf x A/B x 2 K-halves),
//   per phase: ds_read frags | issue 1 half-stage | barrier | setprio(1) |
//   16 MFMA | setprio(0) | barrier.  vmcnt(4) only at phases 1,3 (never 0
//   in steady state) -> staged loads stay in flight across barriers.
// conf pass: conf = e^2 * (1/rs) * (1/cs) in place; finalize gated by rowmax.

#define Ncst 2
#define Lc 4800
#define Sc 4800
#define Cc 256
#define K2 512          // 2*C expanded K (f16 hi|lo for A, hi|hi for B)
#define LP 4864         // 4800 padded to 19*256
#define THRC 0.2f

typedef float f32x4 __attribute__((ext_vector_type(4)));
typedef _Float16 f16x8 __attribute__((ext_vector_type(8)));

#define AS1(p) ((__attribute__((address_space(1))) void*)(p))
#define AS3(p) ((__attribute__((address_space(3))) void*)(p))

// ---------------- conversion (+ zero accumulators): A2/B2 [N][LP][512] f16 --
// A2 segments: [a_hi | a_lo]; B2: [b_hi | b_hi] => dot over 512 = hi.hi + lo.hi
__global__ __launch_bounds__(256) void convert_kernel(
    const float* __restrict__ f0, const float* __restrict__ f1,
    unsigned short* __restrict__ A2, unsigned short* __restrict__ B2,
    float* __restrict__ rs, float* __restrict__ cs)
{
    int idx = blockIdx.x * 256 + threadIdx.x;      // over N*LP*(C/8)
    if (idx < Ncst * Lc) { rs[idx] = 0.f; cs[idx] = 0.f; }   // fold init
    if (idx >= Ncst * LP * (Cc / 8)) return;
    int k8  = idx & (Cc / 8 - 1);                  // 0..31
    int row = (idx >> 5) % LP;
    int n   = idx / (LP * (Cc / 8));
    size_t base = ((size_t)n * LP + row) * K2 + k8 * 8;

    float av[8], bv[8];
    if (row < Lc) {
        const float4* pa = (const float4*)(f0 + ((size_t)n * Lc + row) * Cc + k8 * 8);
        float4 a0 = pa[0], a1 = pa[1];
        av[0]=a0.x; av[1]=a0.y; av[2]=a0.z; av[3]=a0.w;
        av[4]=a1.x; av[5]=a1.y; av[6]=a1.z; av[7]=a1.w;
        const float4* pb = (const float4*)(f1 + ((size_t)n * Sc + row) * Cc + k8 * 8);
        float4 b0 = pb[0], b1 = pb[1];
        bv[0]=b0.x; bv[1]=b0.y; bv[2]=b0.z; bv[3]=b0.w;
        bv[4]=b1.x; bv[5]=b1.y; bv[6]=b1.z; bv[7]=b1.w;
    } else {
        for (int i = 0; i < 8; ++i) { av[i] = 0.f; bv[i] = 0.f; }
    }

    _Float16 ahi[8], alo[8], bhi[8];
#pragma unroll
    for (int i = 0; i < 8; ++i) {
        _Float16 h = (_Float16)av[i];
        ahi[i] = h;
        alo[i] = (_Float16)(av[i] - (float)h);
        bhi[i] = (_Float16)bv[i];
    }
    *(uint4*)&A2[base]       = *(uint4*)ahi;
    *(uint4*)&A2[base + 256] = *(uint4*)alo;
    *(uint4*)&B2[base]       = *(uint4*)bhi;
    *(uint4*)&B2[base + 256] = *(uint4*)bhi;
}

// ---------------- GEMM: 256^2 tile, 8-phase schedule -------------------------
// 8 waves = 512 thr, wave (wm 0..1, wn 0..3): output rows wm*128+127, cols wn*64+63.
// Wave tile 128x64 = acc[8][4] f32x4 via 16x16x32 f16 MFMA.
// LDS: lds[buf2][matA/B][khalf2][256 rows x 4 slots16B]; slot = row*4 + (q ^ ((row>>1)&3))
//   slot q holds k = kh*32 + q*8 .. +8  (pre-swizzled global source, linear dest).
// K-tile t (BK=64): 4 phases = (msub, ksub) in order (0,0)(1,0)(0,1)(1,1).
// Prefetch of tile t+1 halves: ph0 A-kh0, ph1 B-kh0, ph2 A-kh1, ph3 B-kh1
// (2 global_load_lds each). vmcnt(4) before ph1/ph3 pre-MFMA barrier drains
// exactly the halves consumed 2 phases later; 4 loads always stay in flight.
__global__ __launch_bounds__(512, 2) void gemm_kernel(
    const unsigned short* __restrict__ A2, const unsigned short* __restrict__ B2,
    float* __restrict__ eout, float* __restrict__ rs, float* __restrict__ cs)
{
    __shared__ __attribute__((aligned(16))) unsigned short lds[2][2][2][8192]; // 128 KB

    // bijective XCD-aware swizzle over 722 blocks (m204 formula)
    int flat = blockIdx.x + 19 * blockIdx.y + 361 * blockIdx.z;   // 0..721
    int xcd = flat & 7, o8 = flat >> 3;
    const int qc = 722 / 8, rc = 722 % 8;                          // 90, 2
    int wg = (xcd < rc ? xcd * (qc + 1) : rc * (qc + 1) + (xcd - rc) * qc) + o8;
    const int tn = wg % 19;
    const int tm = (wg / 19) % 19;
    const int n  = wg / 361;

    const int tid  = threadIdx.x;
    const int wave = tid >> 6;
    const int lane = tid & 63;
    const int wm   = wave >> 2;     // 0..1
    const int wn   = wave & 3;      // 0..3
    const int ml   = lane & 15;
    const int kq   = lane >> 4;     // 0..3

    const unsigned short* Ab = A2 + ((size_t)n * LP + (size_t)tm * 256) * K2;
    const unsigned short* Bb = B2 + ((size_t)n * LP + (size_t)tn * 256) * K2;

    // staging source pointers: [kh][chunk]; chunk c covers slots c*512+tid
    const unsigned short *pA[2][2], *pB[2][2];
    int sidx_[2];
#pragma unroll
    for (int c = 0; c < 2; ++c) {
        int s = c * 512 + tid;                      // 0..1023
        sidx_[c] = s;
        int row = s >> 2;
        int q   = (s & 3) ^ ((row >> 1) & 3);
#pragma unroll
        for (int kh = 0; kh < 2; ++kh) {
            pA[kh][c] = Ab + (size_t)row * K2 + kh * 32 + q * 8;
            pB[kh][c] = Bb + (size_t)row * K2 + kh * 32 + q * 8;
        }
    }

#define STAGE_A(bb, kh, tt) do { \
    __builtin_amdgcn_global_load_lds(AS1(pA[kh][0] + (tt) * 64), AS3(&lds[bb][0][kh][sidx_[0] * 8]), 16, 0, 0); \
    __builtin_amdgcn_global_load_lds(AS1(pA[kh][1] + (tt) * 64), AS3(&lds[bb][0][kh][sidx_[1] * 8]), 16, 0, 0); \
    } while (0)
#define STAGE_B(bb, kh, tt) do { \
    __builtin_amdgcn_global_load_lds(AS1(pB[kh][0] + (tt) * 64), AS3(&lds[bb][1][kh][sidx_[0] * 8]), 16, 0, 0); \
    __builtin_amdgcn_global_load_lds(AS1(pB[kh][1] + (tt) * 64), AS3(&lds[bb][1][kh][sidx_[1] * 8]), 16, 0, 0); \
    } while (0)
#define READA(bb, m_, ks) do { _Pragma("unroll") for (int i_ = 0; i_ < 4; ++i_) { \
    int r_ = wm * 128 + (m_) * 64 + i_ * 16 + ml; \
    af[i_] = *(const f16x8*)&lds[bb][0][ks][(r_ * 4 + (kq ^ ((r_ >> 1) & 3))) * 8]; } } while (0)
#define READB(bb, ks) do { _Pragma("unroll") for (int j_ = 0; j_ < 4; ++j_) { \
    int r_ = wn * 64 + j_ * 16 + ml; \
    bf_[j_] = *(const f16x8*)&lds[bb][1][ks][(r_ * 4 + (kq ^ ((r_ >> 1) & 3))) * 8]; } } while (0)
#define MFMAQ(m_) do { _Pragma("unroll") for (int i_ = 0; i_ < 4; ++i_) _Pragma("unroll") for (int j_ = 0; j_ < 4; ++j_) \
    acc[(m_) * 4 + i_][j_] = __builtin_amdgcn_mfma_f32_16x16x32_f16(af[i_], bf_[j_], acc[(m_) * 4 + i_][j_], 0, 0, 0); } while (0)

    f32x4 acc[8][4] = {};

    // prologue: stage all of tile 0; kh0 halves must land (oldest 4 of 8)
    STAGE_A(0, 0, 0); STAGE_B(0, 0, 0); STAGE_A(0, 1, 0); STAGE_B(0, 1, 0);
    asm volatile("s_waitcnt vmcnt(4)" ::: "memory");
    __builtin_amdgcn_s_barrier();

#pragma unroll
    for (int t = 0; t < 8; ++t) {
        const int b  = t & 1;
        const int nb = b ^ 1;
        const bool pf = (t < 7);
        f16x8 af[4], bf_[4];
        // ---- phase 0: (msub0, ks0)
        READB(b, 0); READA(b, 0, 0);
        if (pf) STAGE_A(nb, 0, t + 1);
        __builtin_amdgcn_s_barrier();
        __builtin_amdgcn_s_setprio(1); MFMAQ(0); __builtin_amdgcn_s_setprio(0);
        __builtin_amdgcn_s_barrier();
        // ---- phase 1: (msub1, ks0); gate kh1 halves (consumed ph2/ph3)
        READA(b, 1, 0);
        if (pf) { STAGE_B(nb, 0, t + 1); asm volatile("s_waitcnt vmcnt(4)" ::: "memory"); }
        else    { asm volatile("s_waitcnt vmcnt(0)" ::: "memory"); }
        __builtin_amdgcn_s_barrier();
        __builtin_amdgcn_s_setprio(1); MFMAQ(1); __builtin_amdgcn_s_setprio(0);
        __builtin_amdgcn_s_barrier();
        // ---- phase 2: (msub0, ks1)
        READB(b, 1); READA(b, 0, 1);
        if (pf) STAGE_A(nb, 1, t + 1);
        __builtin_amdgcn_s_barrier();
        __builtin_amdgcn_s_setprio(1); MFMAQ(0); __builtin_amdgcn_s_setprio(0);
        __builtin_amdgcn_s_barrier();
        // ---- phase 3: (msub1, ks1); gate next tile's kh0 halves
        READA(b, 1, 1);
        if (pf) { STAGE_B(nb, 1, t + 1); asm volatile("s_waitcnt vmcnt(4)" ::: "memory"); }
        __builtin_amdgcn_s_barrier();
        __builtin_amdgcn_s_setprio(1); MFMAQ(1); __builtin_amdgcn_s_setprio(0);
        __builtin_amdgcn_s_barrier();
    }

    // ---- epilogue: e = exp(alpha*sim); store; accumulate row/col sums ----
    // D frag: col = ml, row = kq*4 + r; acc[ii][j] <-> rows wm*128+ii*16, cols wn*64+j*16
    const float alpha = 5.0f / 128.0f;          // 1/(256*0.1), exact in fp32
#pragma unroll
    for (int ii = 0; ii < 8; ++ii) {
#pragma unroll
        for (int r = 0; r < 4; ++r) {
            int gl = tm * 256 + wm * 128 + ii * 16 + kq * 4 + r;
            bool rok = gl < Lc;
#pragma unroll
            for (int j = 0; j < 4; ++j) {
                int gs = tn * 256 + wn * 64 + j * 16 + ml;
                bool ok = rok && (gs < Sc);
                float ev = ok ? __expf(acc[ii][j][r] * alpha) : 0.f;
                acc[ii][j][r] = ev;
                if (ok) eout[((size_t)n * Lc + gl) * Sc + gs] = ev;
            }
        }
    }
    // row sums: reduce over j and ml lanes (xor 1,2,4,8 stays in quarter)
#pragma unroll
    for (int ii = 0; ii < 8; ++ii) {
#pragma unroll
        for (int r = 0; r < 4; ++r) {
            float rp = acc[ii][0][r] + acc[ii][1][r] + acc[ii][2][r] + acc[ii][3][r];
            rp += __shfl_xor(rp, 1);
            rp += __shfl_xor(rp, 2);
            rp += __shfl_xor(rp, 4);
            rp += __shfl_xor(rp, 8);
            int gl = tm * 256 + wm * 128 + ii * 16 + kq * 4 + r;
            if (ml == 0 && gl < Lc) atomicAdd(&rs[(size_t)n * Lc + gl], rp);
        }
    }
    // col sums: reduce over ii,r and kq (xor 16, 32)
#pragma unroll
    for (int j = 0; j < 4; ++j) {
        float cp = 0.f;
#pragma unroll
        for (int ii = 0; ii < 8; ++ii)
#pragma unroll
            for (int r = 0; r < 4; ++r) cp += acc[ii][j][r];
        cp += __shfl_xor(cp, 16);
        cp += __shfl_xor(cp, 32);
        int gs = tn * 256 + wn * 64 + j * 16 + ml;
        if (kq == 0 && gs < Sc) atomicAdd(&cs[(size_t)n * Sc + gs], cp);
    }
#undef STAGE_A
#undef STAGE_B
#undef READA
#undef READB
#undef MFMAQ
}

// ---------------- reciprocal of sums ----------------------------------------
__global__ __launch_bounds__(256) void inv_kernel(
    const float* __restrict__ rs, const float* __restrict__ cs,
    float* __restrict__ rsinv, float* __restrict__ csinv)
{
    int i = blockIdx.x * 256 + threadIdx.x;
    if (i < Ncst * Lc) { rsinv[i] = 1.0f / rs[i]; csinv[i] = 1.0f / cs[i]; }
}

// ---------------- conf: in-place e -> conf = e^2*rsinv*csinv; row conf max ---
__global__ __launch_bounds__(256) void conf_kernel(
    float* __restrict__ confio,
    const float* __restrict__ rsinv, const float* __restrict__ csinv,
    float* __restrict__ rcm)
{
    __shared__ float sw[4];
    int b = blockIdx.x;                          // n*Lc + l
    int n = b / Lc;
    f32x4* row = (f32x4*)(confio + (size_t)b * Sc);
    const f32x4* civ = (const f32x4*)(csinv + (size_t)n * Sc);
    int tid = threadIdx.x;
    float riv = rsinv[b];
    float lmax = 0.f;
    for (int v = tid; v < Sc / 4; v += 256) {
        f32x4 e4 = row[v];
        f32x4 c4 = civ[v];
        f32x4 o  = e4 * e4 * riv * c4;
        row[v] = o;
        lmax = fmaxf(lmax, fmaxf(fmaxf(o.x, o.y), fmaxf(o.z, o.w)));
    }
#pragma unroll
    for (int off = 1; off < 64; off <<= 1) lmax = fmaxf(lmax, __shfl_xor(lmax, off));
    if ((tid & 63) == 0) sw[tid >> 6] = lmax;
    __syncthreads();
    if (tid == 0) rcm[b] = fmaxf(fmaxf(sw[0], sw[1]), fmaxf(sw[2], sw[3]));
}

// ---------------- finalize: threshold + border + mutual-NN -------------------
__global__ __launch_bounds__(256) void finalize_kernel(
    const float* __restrict__ conf, const float* __restrict__ rcm,
    const int* __restrict__ h0p, const int* __restrict__ w0p,
    const int* __restrict__ h1p, const int* __restrict__ w1p,
    float* __restrict__ out_match, float* __restrict__ out_j, float* __restrict__ out_mconf)
{
    int i = blockIdx.x * 256 + threadIdx.x;      // n*Lc + l
    if (i >= Ncst * Lc) return;
    int n = i / Lc, l = i % Lc;
    float mm = rcm[i];
    float fm = 0.f, fj = 0.f, fc = 0.f;
    if (mm > THRC) {
        int w0 = *w0p, w1 = *w1p;
        if ((l / w0) >= 2 && (l % w0) >= 2) {
            const float* rowp = conf + ((size_t)n * Lc + l) * Sc;
            for (int s = 0; s < Sc; ++s) {
                float c = rowp[s];
                if (c == mm && (s / w1) >= 2 && (s % w1) >= 2) {
                    bool ismax = true;
                    const float* colp = conf + (size_t)n * Lc * Sc + s;
                    for (int lp = 0; lp < Lc; ++lp) {
                        if (colp[(size_t)lp * Sc] > c) { ismax = false; break; }
                    }
                    if (ismax) { fm = 1.f; fj = (float)s; fc = c; break; }
                }
            }
        }
    }
    out_match[i] = fm; out_j[i] = fj; out_mconf[i] = fc;
}

extern "C" void kernel_launch(void* const* d_in, const int* in_sizes, int n_in,
                              void* d_out, int out_size, void* d_ws, size_t ws_size,
                              hipStream_t stream) {
    const float* f0 = (const float*)d_in[0];
    const float* f1 = (const float*)d_in[1];
    const int* h0p = (const int*)d_in[2];
    const int* w0p = (const int*)d_in[3];
    const int* h1p = (const int*)d_in[4];
    const int* w1p = (const int*)d_in[5];

    // workspace layout (bytes); total ~20.1 MB
    char* ws = (char*)d_ws;
    unsigned short* A2 = (unsigned short*)ws;                  // 9,961,472 B
    unsigned short* B2 = (unsigned short*)(ws + 9961472);      // 9,961,472 B
    float* rs    = (float*)(ws + 19922944);                    // 38,400 B each
    float* cs    = (float*)(ws + 19961344);
    float* rsinv = (float*)(ws + 19999744);
    float* csinv = (float*)(ws + 20038144);
    float* rcm   = (float*)(ws + 20076544);

    float* conf      = (float*)d_out;                          // [N][L][S]: e then conf
    float* out_match = conf + (size_t)Ncst * Lc * Sc;
    float* out_j     = out_match + Ncst * Lc;
    float* out_mconf = out_j + Ncst * Lc;

    convert_kernel<<<(Ncst * LP * (Cc / 8) + 255) / 256, 256, 0, stream>>>(f0, f1, A2, B2, rs, cs);

    dim3 gg(19, 19, Ncst);   // 19 x 19 x 2 = 722 blocks
    gemm_kernel<<<gg, 512, 0, stream>>>(A2, B2, conf, rs, cs);

    inv_kernel<<<(Ncst * Lc + 255) / 256, 256, 0, stream>>>(rs, cs, rsinv, csinv);

    conf_kernel<<<Ncst * Lc, 256, 0, stream>>>(conf, rsinv, csinv, rcm);

    finalize_kernel<<<(Ncst * Lc + 255) / 256, 256, 0, stream>>>(
        conf, rcm, h0p, w0p, h1p, w1p, out_match, out_j, out_mconf);
}